// Round 9
// baseline (49.958 us; speedup 1.0000x reference)
//
#include <hip/hip_runtime.h>
#include <hip/hip_bf16.h>

// QLoRA SwiGLU MLP, B=16 tokens, d=4096, h=11008, r=2.
// tile(wq,(1,4)) => x @ W^T == fold4(x) @ wq^T  (skinny GEMM, K = in/4).
// R9: MFMA core kept; raise TLP. gateup/down -> 512thr/8-wave blocks
// (R8 had 4 waves/CU on k_down -> latency-starved at ~900ns HBM).
// prep2 -> 172 blocks + atomic t2. f32->bf16 via hardware cvt (RNE).
// Fragment maps (verified): A/B: own-idx = lane&15, k = (lane>>4)*8+j;
// C/D: col(n) = lane&15, row(m) = (lane>>4)*4+reg.

#define NB     16
#define DMODEL 4096
#define HID    11008
#define DQ     1024   // DMODEL/4
#define HQ     2752   // HID/4

// workspace layout (float offsets)
#define XSB_OFF 0         // xs bf16 [16][1024] = 8192 floats
#define T1_OFF  8192      // [16][2] f32
#define T3_OFF  8224
#define HVT_OFF 8256      // hvecT f32 [11008][16]
#define HSB_OFF 184384    // hs bf16 [16][2752] = 22016 floats
#define T2_OFF  206400    // [16][2] f32

typedef __attribute__((ext_vector_type(8))) short bf16x8;
typedef __attribute__((ext_vector_type(4))) float f32x4;

__device__ __forceinline__ unsigned short f2bfh(float f) {
  __hip_bfloat16 h = __float2bfloat16(f);   // v_cvt, RNE
  return __builtin_bit_cast(unsigned short, h);
}
__device__ __forceinline__ unsigned pack2(float lo, float hi) {
  return (unsigned)f2bfh(lo) | ((unsigned)f2bfh(hi) << 16);
}
__device__ __forceinline__ bf16x8 cvt8(const float4 a, const float4 b) {
  uint4 u = make_uint4(pack2(a.x, a.y), pack2(a.z, a.w),
                       pack2(b.x, b.y), pack2(b.z, b.w));
  return __builtin_bit_cast(bf16x8, u);
}

// ---------------------------------------------------------------------------
// prep1: xs[b][j] = sum_k x[b][k*1024+j] stored bf16; t1,t3 = LoRA A dots.
// Also zeroes T2 (block 0) for prep2's atomics.
__global__ __launch_bounds__(256) void k_prep1(const float* __restrict__ x,
                                               const float* __restrict__ a1,
                                               const float* __restrict__ a3,
                                               float* __restrict__ ws) {
  const int b = blockIdx.x, t = threadIdx.x;
  if (b == 0 && t < 32) ws[T2_OFF + t] = 0.f;

  const float4* x4  = (const float4*)(x) + b * (DMODEL / 4);
  const float4* a14 = (const float4*)a1;
  const float4* a34 = (const float4*)a3;
  float4 xs = make_float4(0.f, 0.f, 0.f, 0.f);
  float s10 = 0.f, s11 = 0.f, s30 = 0.f, s31 = 0.f;
#pragma unroll
  for (int k = 0; k < 4; ++k) {
    float4 xv  = x4[k * 256 + t];
    xs.x += xv.x; xs.y += xv.y; xs.z += xv.z; xs.w += xv.w;
    float4 a10 = a14[k * 256 + t];
    float4 a11 = a14[1024 + k * 256 + t];
    float4 a30 = a34[k * 256 + t];
    float4 a31 = a34[1024 + k * 256 + t];
    s10 += xv.x * a10.x + xv.y * a10.y + xv.z * a10.z + xv.w * a10.w;
    s11 += xv.x * a11.x + xv.y * a11.y + xv.z * a11.z + xv.w * a11.w;
    s30 += xv.x * a30.x + xv.y * a30.y + xv.z * a30.z + xv.w * a30.w;
    s31 += xv.x * a31.x + xv.y * a31.y + xv.z * a31.z + xv.w * a31.w;
  }
  ((uint2*)(ws + XSB_OFF))[b * 256 + t] =
      make_uint2(pack2(xs.x, xs.y), pack2(xs.z, xs.w));

  __shared__ float4 rb[256];
  rb[t] = make_float4(s10, s11, s30, s31);
  __syncthreads();
  for (int s = 128; s > 0; s >>= 1) {
    if (t < s) {
      rb[t].x += rb[t + s].x; rb[t].y += rb[t + s].y;
      rb[t].z += rb[t + s].z; rb[t].w += rb[t + s].w;
    }
    __syncthreads();
  }
  if (t == 0) {
    ws[T1_OFF + b * 2]     = rb[0].x;
    ws[T1_OFF + b * 2 + 1] = rb[0].y;
    ws[T3_OFF + b * 2]     = rb[0].z;
    ws[T3_OFF + b * 2 + 1] = rb[0].w;
  }
}

// ---------------------------------------------------------------------------
// gateup: 688 blocks x 512 thr (8 waves). Tile = 16 out cols; wave w owns
// K-chunk [w*128, w*128+128) = 4 kk steps. LDS reduce, epilogue in wave 0.
__global__ __launch_bounds__(512) void k_gateup(const float* __restrict__ w1q,
                                                const float* __restrict__ w3q,
                                                const float* __restrict__ b1,
                                                const float* __restrict__ b3,
                                                const float* __restrict__ ws,
                                                float* __restrict__ hvecT) {
  __shared__ float red[8][8][64];
  const int t = threadIdx.x, w = t >> 6, l = t & 63;
  const int tile = blockIdx.x;
  const int n  = l & 15;            // token col / weight row selector
  const int kb = (l >> 4) * 8;      // k sub-offset within each 32-block
  const int o  = tile * 16 + n;
  const unsigned short* xsb = (const unsigned short*)(ws + XSB_OFF);

  f32x4 acc1 = {0.f, 0.f, 0.f, 0.f}, acc3 = {0.f, 0.f, 0.f, 0.f};
  const int k0 = w * 128;
#pragma unroll
  for (int kk = 0; kk < 4; ++kk) {
    const int kabs = k0 + kk * 32 + kb;
    const float4* p1 = (const float4*)(w1q + (size_t)o * DQ + kabs);
    const float4* p3 = (const float4*)(w3q + (size_t)o * DQ + kabs);
    const bf16x8 bb = *(const bf16x8*)(xsb + n * DQ + kabs);
    const bf16x8 a1f = cvt8(p1[0], p1[1]);
    const bf16x8 a3f = cvt8(p3[0], p3[1]);
    acc1 = __builtin_amdgcn_mfma_f32_16x16x32_bf16(a1f, bb, acc1, 0, 0, 0);
    acc3 = __builtin_amdgcn_mfma_f32_16x16x32_bf16(a3f, bb, acc3, 0, 0, 0);
  }
#pragma unroll
  for (int r = 0; r < 4; ++r) {
    red[w][r][l]     = acc1[r];
    red[w][r + 4][l] = acc3[r];
  }
  __syncthreads();
  if (w == 0) {
    const float t10 = ws[T1_OFF + 2 * n], t11 = ws[T1_OFF + 2 * n + 1];
    const float t30 = ws[T3_OFF + 2 * n], t31 = ws[T3_OFF + 2 * n + 1];
    const int m4 = (l >> 4) * 4;
#pragma unroll
    for (int r = 0; r < 4; ++r) {
      float g0 = 0.f, u0 = 0.f;
#pragma unroll
      for (int ww = 0; ww < 8; ++ww) {
        g0 += red[ww][r][l];
        u0 += red[ww][r + 4][l];
      }
      const int oo = tile * 16 + m4 + r;
      const float g = g0 + 0.5f * (t10 * b1[2 * oo] + t11 * b1[2 * oo + 1]);
      const float u = u0 + 0.5f * (t30 * b3[2 * oo] + t31 * b3[2 * oo + 1]);
      hvecT[oo * 16 + n] = (g / (1.f + __expf(-g))) * u;
    }
  }
}

// ---------------------------------------------------------------------------
// prep2: 172 blocks x 256 thr. Thread (b = t>>4, jl = t&15) handles
// j = blk*16+jl: hs[b][j] = fold4(hvec) stored bf16; t2 partials via
// 16-lane shfl reduce + atomicAdd (T2 zeroed by prep1).
__global__ __launch_bounds__(256) void k_prep2(const float* __restrict__ hvecT,
                                               const float* __restrict__ a2,
                                               float* __restrict__ ws) {
  const int t = threadIdx.x;
  const int b = t >> 4, jl = t & 15;
  const int j = blockIdx.x * 16 + jl;
  unsigned short* hsb = (unsigned short*)(ws + HSB_OFF);

  const float v0 = hvecT[(size_t)j * 16 + b];
  const float v1 = hvecT[(size_t)(j + HQ) * 16 + b];
  const float v2 = hvecT[(size_t)(j + 2 * HQ) * 16 + b];
  const float v3 = hvecT[(size_t)(j + 3 * HQ) * 16 + b];
  hsb[b * HQ + j] = f2bfh(v0 + v1 + v2 + v3);

  float s0 = v0 * a2[j] + v1 * a2[j + HQ] +
             v2 * a2[j + 2 * HQ] + v3 * a2[j + 3 * HQ];
  float s1 = v0 * a2[HID + j] + v1 * a2[HID + j + HQ] +
             v2 * a2[HID + j + 2 * HQ] + v3 * a2[HID + j + 3 * HQ];
#pragma unroll
  for (int off = 1; off < 16; off <<= 1) {
    s0 += __shfl_xor(s0, off);
    s1 += __shfl_xor(s1, off);
  }
  if (jl == 0) {
    atomicAdd(&ws[T2_OFF + 2 * b], s0);
    atomicAdd(&ws[T2_OFF + 2 * b + 1], s1);
  }
}

// ---------------------------------------------------------------------------
// down: 256 blocks x 512 thr (8 waves). Tile = 16 out cols; K=2752 = 86 kk
// split {11,11,11,11,11,11,10,10} across waves. LDS reduce, epilogue wave 0.
__global__ __launch_bounds__(512) void k_down(const float* __restrict__ w2q,
                                              const float* __restrict__ b2,
                                              const float* __restrict__ ws,
                                              float* __restrict__ out) {
  __shared__ float red[8][4][64];
  const int t = threadIdx.x, w = t >> 6, l = t & 63;
  const int tile = blockIdx.x;
  const int n  = l & 15;
  const int kb = (l >> 4) * 8;
  const int o  = tile * 16 + n;
  const unsigned short* hsb = (const unsigned short*)(ws + HSB_OFF);

  f32x4 acc = {0.f, 0.f, 0.f, 0.f};
  const int kks  = (w < 6) ? w * 11 : 66 + (w - 6) * 10;
  const int klen = (w < 6) ? 11 : 10;
#pragma unroll
  for (int kk = 0; kk < 11; ++kk) {
    if (kk < klen) {                      // wave-uniform guard
      const int kabs = (kks + kk) * 32 + kb;
      const float4* p2 = (const float4*)(w2q + (size_t)o * HQ + kabs);
      const bf16x8 bb = *(const bf16x8*)(hsb + n * HQ + kabs);
      const bf16x8 af = cvt8(p2[0], p2[1]);
      acc = __builtin_amdgcn_mfma_f32_16x16x32_bf16(af, bb, acc, 0, 0, 0);
    }
  }
#pragma unroll
  for (int r = 0; r < 4; ++r) red[w][r][l] = acc[r];
  __syncthreads();
  if (w == 0) {
    const float t20 = ws[T2_OFF + 2 * n], t21 = ws[T2_OFF + 2 * n + 1];
    const int m4 = (l >> 4) * 4;
#pragma unroll
    for (int r = 0; r < 4; ++r) {
      float v = 0.f;
#pragma unroll
      for (int ww = 0; ww < 8; ++ww) v += red[ww][r][l];
      const int oo = tile * 16 + m4 + r;
      out[n * DMODEL + oo] = v + 0.5f * (t20 * b2[2 * oo] + t21 * b2[2 * oo + 1]);
    }
  }
}

// ---------------------------------------------------------------------------
extern "C" void kernel_launch(void* const* d_in, const int* in_sizes, int n_in,
                              void* d_out, int out_size, void* d_ws, size_t ws_size,
                              hipStream_t stream) {
  const float* x   = (const float*)d_in[0];
  const float* w1q = (const float*)d_in[1];
  const float* a1  = (const float*)d_in[2];
  const float* b1  = (const float*)d_in[3];
  const float* w3q = (const float*)d_in[4];
  const float* a3  = (const float*)d_in[5];
  const float* b3  = (const float*)d_in[6];
  const float* w2q = (const float*)d_in[7];
  const float* a2  = (const float*)d_in[8];
  const float* b2  = (const float*)d_in[9];
  float* out = (float*)d_out;
  float* ws  = (float*)d_ws;
  float* hvecT = ws + HVT_OFF;

  k_prep1<<<16, 256, 0, stream>>>(x, a1, a3, ws);
  k_gateup<<<HID / 16, 512, 0, stream>>>(w1q, w3q, b1, b3, ws, hvecT);
  k_prep2<<<HQ / 16, 256, 0, stream>>>(hvecT, a2, ws);
  k_down<<<DMODEL / 16, 512, 0, stream>>>(w2q, b2, ws, out);
}